// Round 5
// baseline (69.029 us; speedup 1.0000x reference)
//
#include <hip/hip_runtime.h>
#include <hip/hip_bf16.h>
#include <math.h>

// Problem: B=4, L=4096, D=1024, NB=4, TOPK=2
//   logits = x @ gate_w + gate_b          (B,L,4)
//   top-2 mask (keep logits >= 2nd-largest), softmax
//   out = sum_n w[n] * branches[:,:,n,:]  (B,L,D)
//
// Fused, ONE row per wave (16384 waves, no grid-stride loop): every wave
// issues all its loads once (x, gate_w, 16 branch vectors) before the
// serial shuffle-reduce + exp phase, then blends and exits. No mid-kernel
// memory bubble from a second grid-stride iteration. Non-temporal hints on
// the 384MB stream (footprint > 256MB L3, zero reuse).

#define DDIM 1024
#define NBR 4

typedef float f32x4 __attribute__((ext_vector_type(4)));

__global__ __launch_bounds__(256) void titan_fused_kernel(
    const float* __restrict__ x,
    const float* __restrict__ branches,
    const float* __restrict__ gate_w,
    const float* __restrict__ gate_b,
    float* __restrict__ out,
    int nrows)
{
    const int lane = threadIdx.x & 63;
    const int wave = threadIdx.x >> 6;
    const int waves_per_block = blockDim.x >> 6;
    const int row = blockIdx.x * waves_per_block + wave;
    if (row >= nrows) return;
    const int d0 = lane * 4;

    const float* xr = x + (size_t)row * DDIM;
    const float* br = branches + (size_t)row * (NBR * DDIM);
    float* outr = out + (size_t)row * DDIM;

    // ---- issue ALL loads up front ----
    // x: 4 vectors (needed first for the dot)
    f32x4 xv[4];
#pragma unroll
    for (int j = 0; j < 4; ++j)
        xv[j] = __builtin_nontemporal_load((const f32x4*)(xr + j * 256 + d0));

    // gate_w slice: lane owns dims d = j*256 + lane*4 + k; (D,NB) row-major
    // -> 4 weights per dim are one contiguous float4 (L2-resident, 16 KB).
    f32x4 gw[4][4];
#pragma unroll
    for (int j = 0; j < 4; ++j)
#pragma unroll
        for (int k = 0; k < 4; ++k)
            gw[j][k] = *(const f32x4*)(gate_w + (size_t)((j * 256 + d0 + k) * NBR));

    // branches: 16 vectors, streaming
    f32x4 bb[4][4];  // [j][n]
#pragma unroll
    for (int j = 0; j < 4; ++j)
#pragma unroll
        for (int n = 0; n < NBR; ++n)
            bb[j][n] = __builtin_nontemporal_load(
                (const f32x4*)(br + n * DDIM + j * 256 + d0));

    const f32x4 gb = *(const f32x4*)gate_b;

    // ---- gating matvec (consumes xv+gw; branch loads keep flying) ----
    float a0 = 0.f, a1 = 0.f, a2 = 0.f, a3 = 0.f;
#pragma unroll
    for (int j = 0; j < 4; ++j) {
#pragma unroll
        for (int k = 0; k < 4; ++k) {
            const float xs = xv[j][k];
            a0 = fmaf(xs, gw[j][k].x, a0);
            a1 = fmaf(xs, gw[j][k].y, a1);
            a2 = fmaf(xs, gw[j][k].z, a2);
            a3 = fmaf(xs, gw[j][k].w, a3);
        }
    }

    // ---- 64-lane tree reduce; branch loads still in flight ----
#pragma unroll
    for (int off = 32; off >= 1; off >>= 1) {
        a0 += __shfl_xor(a0, off, 64);
        a1 += __shfl_xor(a1, off, 64);
        a2 += __shfl_xor(a2, off, 64);
        a3 += __shfl_xor(a3, off, 64);
    }

    float lg[NBR] = {a0 + gb.x, a1 + gb.y, a2 + gb.z, a3 + gb.w};

    // top-2 threshold (keep logits >= 2nd-largest; duplicates kept)
    float m1 = -INFINITY, m2 = -INFINITY;
#pragma unroll
    for (int n = 0; n < NBR; ++n) {
        const float v = lg[n];
        if (v > m1) { m2 = m1; m1 = v; }
        else if (v > m2) { m2 = v; }
    }
    float w[NBR]; float sum = 0.f;
#pragma unroll
    for (int n = 0; n < NBR; ++n) {
        const float e = (lg[n] >= m2) ? expf(lg[n] - m1) : 0.0f;
        w[n] = e; sum += e;
    }
    const float inv = 1.0f / sum;
#pragma unroll
    for (int n = 0; n < NBR; ++n) w[n] *= inv;

    // ---- blend: consume the prefetched branch vectors ----
#pragma unroll
    for (int j = 0; j < 4; ++j) {
        f32x4 o;
        o.x = w[0] * bb[j][0].x + w[1] * bb[j][1].x + w[2] * bb[j][2].x + w[3] * bb[j][3].x;
        o.y = w[0] * bb[j][0].y + w[1] * bb[j][1].y + w[2] * bb[j][2].y + w[3] * bb[j][3].y;
        o.z = w[0] * bb[j][0].z + w[1] * bb[j][1].z + w[2] * bb[j][2].z + w[3] * bb[j][3].z;
        o.w = w[0] * bb[j][0].w + w[1] * bb[j][1].w + w[2] * bb[j][2].w + w[3] * bb[j][3].w;
        __builtin_nontemporal_store(o, (f32x4*)(outr + j * 256 + d0));
    }
}

extern "C" void kernel_launch(void* const* d_in, const int* in_sizes, int n_in,
                              void* d_out, int out_size, void* d_ws, size_t ws_size,
                              hipStream_t stream) {
    const float* x        = (const float*)d_in[0];
    const float* branches = (const float*)d_in[1];
    const float* gate_w   = (const float*)d_in[2];
    const float* gate_b   = (const float*)d_in[3];
    float* out = (float*)d_out;

    const int nrows = in_sizes[0] / DDIM;  // B*L = 16384

    const int block = 256;                       // 4 waves/block, 1 row/wave
    const int grid = (nrows + 3) / 4;            // 4096 blocks
    hipLaunchKernelGGL(titan_fused_kernel, dim3(grid), dim3(block), 0, stream,
                       x, branches, gate_w, gate_b, out, nrows);
}

// Round 6
// 67.963 us; speedup vs baseline: 1.0157x; 1.0157x over previous
//
#include <hip/hip_runtime.h>
#include <hip/hip_bf16.h>
#include <math.h>

// Problem: B=4, L=4096, D=1024, NB=4, TOPK=2
//   logits = x @ gate_w + gate_b          (B,L,4)
//   top-2 mask (keep logits >= 2nd-largest), softmax
//   out = sum_n w[n] * branches[:,:,n,:]  (B,L,D)
//
// Final form (R3, 67.9 us = 5.93 TB/s effective, 94% of float4-copy ceiling):
// fused, one wave per row, grid-stride 2 rows/wave. All 20 16B loads
// (x + 16 branch vectors) issued BEFORE the shuffle-reduce chain so the
// HBM pipe stays busy during the serial reduce+exp phase. Non-temporal
// hints on the 384MB stream (footprint > 256MB L3, zero reuse).

#define DDIM 1024
#define NBR 4

typedef float f32x4 __attribute__((ext_vector_type(4)));

__global__ __launch_bounds__(256) void titan_fused_kernel(
    const float* __restrict__ x,
    const float* __restrict__ branches,
    const float* __restrict__ gate_w,
    const float* __restrict__ gate_b,
    float* __restrict__ out,
    int nrows)
{
    const int lane = threadIdx.x & 63;
    const int wave = threadIdx.x >> 6;
    const int waves_per_block = blockDim.x >> 6;
    const int total_waves = gridDim.x * waves_per_block;
    const int wave_id = blockIdx.x * waves_per_block + wave;
    const int d0 = lane * 4;

    // Preload gate_w slice (reused across this wave's rows).
    // Lane owns dims d = j*256 + lane*4 + k; gate_w (D,NB) row-major ->
    // the 4 weights of dim d are one contiguous float4.
    f32x4 gw[4][4];
#pragma unroll
    for (int j = 0; j < 4; ++j)
#pragma unroll
        for (int k = 0; k < 4; ++k)
            gw[j][k] = *(const f32x4*)(gate_w + (size_t)((j * 256 + d0 + k) * NBR));
    const f32x4 gb = *(const f32x4*)gate_b;

    for (int row = wave_id; row < nrows; row += total_waves) {
        const float* xr = x + (size_t)row * DDIM;
        const float* br = branches + (size_t)row * (NBR * DDIM);
        float* outr = out + (size_t)row * DDIM;

        // ---- issue ALL loads up front: 4 x-vectors, then 16 branch-vectors ----
        f32x4 xv[4];
#pragma unroll
        for (int j = 0; j < 4; ++j)
            xv[j] = __builtin_nontemporal_load((const f32x4*)(xr + j * 256 + d0));

        f32x4 bb[4][4];  // [j][n]
#pragma unroll
        for (int j = 0; j < 4; ++j)
#pragma unroll
            for (int n = 0; n < NBR; ++n)
                bb[j][n] = __builtin_nontemporal_load(
                    (const f32x4*)(br + n * DDIM + j * 256 + d0));

        // ---- gating matvec (needs only xv; branch loads keep flying) ----
        float a0 = 0.f, a1 = 0.f, a2 = 0.f, a3 = 0.f;
#pragma unroll
        for (int j = 0; j < 4; ++j) {
#pragma unroll
            for (int k = 0; k < 4; ++k) {
                const float xs = xv[j][k];
                a0 = fmaf(xs, gw[j][k].x, a0);
                a1 = fmaf(xs, gw[j][k].y, a1);
                a2 = fmaf(xs, gw[j][k].z, a2);
                a3 = fmaf(xs, gw[j][k].w, a3);
            }
        }

        // ---- 64-lane tree reduce; branch loads still in flight ----
#pragma unroll
        for (int off = 32; off >= 1; off >>= 1) {
            a0 += __shfl_xor(a0, off, 64);
            a1 += __shfl_xor(a1, off, 64);
            a2 += __shfl_xor(a2, off, 64);
            a3 += __shfl_xor(a3, off, 64);
        }

        float lg[NBR] = {a0 + gb.x, a1 + gb.y, a2 + gb.z, a3 + gb.w};

        // top-2 threshold (keep logits >= 2nd-largest; duplicates kept)
        float m1 = -INFINITY, m2 = -INFINITY;
#pragma unroll
        for (int n = 0; n < NBR; ++n) {
            const float v = lg[n];
            if (v > m1) { m2 = m1; m1 = v; }
            else if (v > m2) { m2 = v; }
        }
        float w[NBR]; float sum = 0.f;
#pragma unroll
        for (int n = 0; n < NBR; ++n) {
            const float e = (lg[n] >= m2) ? expf(lg[n] - m1) : 0.0f;
            w[n] = e; sum += e;
        }
        const float inv = 1.0f / sum;
#pragma unroll
        for (int n = 0; n < NBR; ++n) w[n] *= inv;

        // ---- blend: consume the prefetched branch vectors ----
#pragma unroll
        for (int j = 0; j < 4; ++j) {
            f32x4 o;
            o.x = w[0] * bb[j][0].x + w[1] * bb[j][1].x + w[2] * bb[j][2].x + w[3] * bb[j][3].x;
            o.y = w[0] * bb[j][0].y + w[1] * bb[j][1].y + w[2] * bb[j][2].y + w[3] * bb[j][3].y;
            o.z = w[0] * bb[j][0].z + w[1] * bb[j][1].z + w[2] * bb[j][2].z + w[3] * bb[j][3].z;
            o.w = w[0] * bb[j][0].w + w[1] * bb[j][1].w + w[2] * bb[j][2].w + w[3] * bb[j][3].w;
            __builtin_nontemporal_store(o, (f32x4*)(outr + j * 256 + d0));
        }
    }
}

extern "C" void kernel_launch(void* const* d_in, const int* in_sizes, int n_in,
                              void* d_out, int out_size, void* d_ws, size_t ws_size,
                              hipStream_t stream) {
    const float* x        = (const float*)d_in[0];
    const float* branches = (const float*)d_in[1];
    const float* gate_w   = (const float*)d_in[2];
    const float* gate_b   = (const float*)d_in[3];
    float* out = (float*)d_out;

    const int nrows = in_sizes[0] / DDIM;  // B*L = 16384

    const int block = 256;                  // 4 waves/block
    const int grid = 2048;                  // 8192 waves -> 2 rows per wave
    hipLaunchKernelGGL(titan_fused_kernel, dim3(grid), dim3(block), 0, stream,
                       x, branches, gate_w, gate_b, out, nrows);
}